// Round 16
// baseline (491.641 us; speedup 1.0000x reference)
//
#include <hip/hip_runtime.h>
#include <math.h>

// Greedy farthest-point selection via precomputed Gram triangle.
// kgram<DOSEL>: R9's proven engine (64x64-tile MFMA f16 2-way split, dbuf LDS,
//   one barrier/chunk, reg prefetch). With DOSEL: after G writes, a per-batch
//   completion counter (device-scope atomic + threadfence) lets the LAST of
//   the batch's 15 blocks run the greedy selection in-kernel -> the serial
//   63-step argmin chain overlaps other batches' gram compute. No spin/
//   deadlock: the 15th arriver proceeds immediately (all writers done).
// kgath: gather-only, 4 blocks/batch (512 blocks, pure streaming).
// Fallback (tiny ws): kgram<false> + split kselect/kgather, G in out_v.

constexpr int BB = 128, NN = 300, DV = 1024, DA = 128, KK = 64;
constexpr int TRI = NN * (NN + 1) / 2;        // 45150
constexpr int TB = 64;
constexpr int NTILES = 15;
constexpr int KC = 32;
constexpr int NCH = DV / KC;                  // 32 chunks
constexpr int LDH = 36;                       // f16 row stride: 72 B

// ws layout
constexpr size_t G_BYTES = (size_t)BB * TRI * 4;       // 23,116,800
constexpr size_t CNT_OFF = G_BYTES;                    // 128 x int
constexpr size_t IDX_OFF = CNT_OFF + 512;              // 128 x 64 x int
constexpr size_t WS_NEED = IDX_OFF + (size_t)BB * KK * 4;

__device__ __constant__ int c_ib[NTILES] = {0,0,0,0,0, 1,1,1,1, 2,2,2, 3,3, 4};
__device__ __constant__ int c_jb[NTILES] = {0,1,2,3,4, 1,2,3,4, 2,3,4, 3,4, 4};

typedef _Float16 f16x8 __attribute__((ext_vector_type(8)));
typedef float    f32x4 __attribute__((ext_vector_type(4)));

union H4 { _Float16 h[4]; uint2 u; };
union F8 { uint2 u2[2]; f16x8 v; };

__device__ __forceinline__ int tri_base(int i) { return i * NN - (i * (i - 1)) / 2; }

// ---- greedy selection for one batch, one wave (R5-proven decision sequence) ----
__device__ __forceinline__ void select_wave_tri(const float* __restrict__ Gb,
                                                int lane, int* s_sorted) {
    float best[5];
    int myidx = 0;

    #pragma unroll
    for (int q = 0; q < 5; ++q) {
        int r = lane + 64 * q;
        best[q] = (r < NN) ? Gb[r] : 3.4e38f;
    }

    int last;
    {
        float v = INFINITY; int ri = 1 << 30;
        #pragma unroll
        for (int q = 0; q < 5; ++q)
            if (best[q] < v) { v = best[q]; ri = lane + 64 * q; }
        #pragma unroll
        for (int off = 32; off >= 1; off >>= 1) {
            float ov = __shfl_xor(v, off, 64); int oi = __shfl_xor(ri, off, 64);
            if (ov < v || (ov == v && oi < ri)) { v = ov; ri = oi; }
        }
        last = ri;
    }
    if (lane == 1) myidx = last;

    for (int t = 2; t < KK; ++t) {
        #pragma unroll
        for (int q = 0; q < 5; ++q) {
            int r = lane + 64 * q;
            if (r < NN) {
                int i = min(last, r), j = max(last, r);
                best[q] = fmaxf(best[q], Gb[tri_base(i) + (j - i)]);
            }
        }
        float v = INFINITY; int ri = 1 << 30;
        #pragma unroll
        for (int q = 0; q < 5; ++q)
            if (best[q] < v) { v = best[q]; ri = lane + 64 * q; }
        #pragma unroll
        for (int off = 32; off >= 1; off >>= 1) {
            float ov = __shfl_xor(v, off, 64); int oi = __shfl_xor(ri, off, 64);
            if (ov < v || (ov == v && oi < ri)) { v = ov; ri = oi; }
        }
        last = ri;
        if (lane == t) myidx = last;
    }

    int rank = 0;
    for (int j = 0; j < KK; ++j) {
        int oj = __shfl(myidx, j, 64);
        rank += (oj < myidx) || (oj == myidx && j < lane);
    }
    s_sorted[rank] = myidx;
}

// ---------------- 1. kgram: 64-tile, dbuf, 4 waves (R9-proven) ----------------
template <bool DOSEL>
__global__ __launch_bounds__(256) void kgram(const float* __restrict__ video,
                                             float* __restrict__ G,
                                             int* __restrict__ cnt,
                                             int* __restrict__ idx) {
    const int bid  = blockIdx.x;
    const int swz  = (bid & 7) * 240 + (bid >> 3);      // bijective: 1920=8*240
    const int batch = swz / 15;
    const int tile  = swz - batch * 15;
    const int i0 = c_ib[tile] * TB, j0 = c_jb[tile] * TB;
    const bool diag = (i0 == j0);
    const int tid = threadIdx.x;

    __shared__ _Float16 sH[2][4][TB][LDH];   // [buf][A-hi,A-lo,B-hi,B-lo] 36.9 KB
    __shared__ float    s_part[256];
    __shared__ double   s_inv[2][TB];
    __shared__ int      s_sorted[KK];
    __shared__ int      s_flag;

    const float* vb = video + (size_t)batch * NN * DV;

    // staging role
    const int slab  = tid >> 7;
    const int lrow  = (tid >> 1) & 63;
    const int khalf = tid & 1;
    const int grow  = (slab ? j0 : i0) + lrow;
    const bool rok  = grow < NN;
    const bool stage_on = !(diag && slab == 1);
    const float4* srcb4 = (const float4*)(vb + (size_t)(rok ? grow : 0) * DV);
    const int qbase = khalf * 4;

    // compute role
    const int lane = tid & 63, w = tid >> 6;
    const int wr = w >> 1, wc = w & 1;
    const int g = lane >> 4, c16 = lane & 15;
    const int bplane = diag ? 0 : 2;

    f32x4 acc[2][2];
    #pragma unroll
    for (int fr = 0; fr < 2; ++fr)
        #pragma unroll
        for (int fc = 0; fc < 2; ++fc) acc[fr][fc] = (f32x4){0.f, 0.f, 0.f, 0.f};

    float ps = 0.f;
    float4 ld[4];
    const float4 z4 = make_float4(0.f, 0.f, 0.f, 0.f);

    auto stage_write = [&](int bf) {
        #pragma unroll
        for (int q = 0; q < 4; ++q) {
            float4 v = ld[q];
            ps = fmaf(v.x, v.x, fmaf(v.y, v.y, fmaf(v.z, v.z, fmaf(v.w, v.w, ps))));
            H4 hi, lo;
            _Float16 h0 = (_Float16)v.x, h1 = (_Float16)v.y,
                     h2 = (_Float16)v.z, h3 = (_Float16)v.w;
            hi.h[0] = h0; hi.h[1] = h1; hi.h[2] = h2; hi.h[3] = h3;
            lo.h[0] = (_Float16)(v.x - (float)h0);
            lo.h[1] = (_Float16)(v.y - (float)h1);
            lo.h[2] = (_Float16)(v.z - (float)h2);
            lo.h[3] = (_Float16)(v.w - (float)h3);
            const int p = khalf * 16 + 4 * q;
            *(uint2*)&sH[bf][slab * 2 + 0][lrow][p] = hi.u;
            *(uint2*)&sH[bf][slab * 2 + 1][lrow][p] = lo.u;
        }
    };

    if (stage_on) {
        #pragma unroll
        for (int q = 0; q < 4; ++q) ld[q] = rok ? srcb4[qbase + q] : z4;
        stage_write(0);
        #pragma unroll
        for (int q = 0; q < 4; ++q) ld[q] = rok ? srcb4[8 + qbase + q] : z4;
    }
    __syncthreads();

    for (int kc = 0; kc < NCH; ++kc) {
        const int cur = kc & 1, nxt = cur ^ 1;

        if (stage_on && kc < NCH - 1) stage_write(nxt);
        if (stage_on && kc < NCH - 2) {
            #pragma unroll
            for (int q = 0; q < 4; ++q)
                ld[q] = rok ? srcb4[(kc + 2) * 8 + qbase + q] : z4;
        }

        f16x8 Ah[2], Al[2], Bh[2], Bl[2];
        #pragma unroll
        for (int fr = 0; fr < 2; ++fr) {
            const int row = 32 * wr + 16 * fr + c16;
            F8 t;
            t.u2[0] = *(const uint2*)&sH[cur][0][row][4 * g];
            t.u2[1] = *(const uint2*)&sH[cur][0][row][16 + 4 * g];
            Ah[fr] = t.v;
            t.u2[0] = *(const uint2*)&sH[cur][1][row][4 * g];
            t.u2[1] = *(const uint2*)&sH[cur][1][row][16 + 4 * g];
            Al[fr] = t.v;
        }
        #pragma unroll
        for (int fc = 0; fc < 2; ++fc) {
            const int row = 32 * wc + 16 * fc + c16;
            F8 t;
            t.u2[0] = *(const uint2*)&sH[cur][bplane + 0][row][4 * g];
            t.u2[1] = *(const uint2*)&sH[cur][bplane + 0][row][16 + 4 * g];
            Bh[fc] = t.v;
            t.u2[0] = *(const uint2*)&sH[cur][bplane + 1][row][4 * g];
            t.u2[1] = *(const uint2*)&sH[cur][bplane + 1][row][16 + 4 * g];
            Bl[fc] = t.v;
        }
        #pragma unroll
        for (int fr = 0; fr < 2; ++fr)
            #pragma unroll
            for (int fc = 0; fc < 2; ++fc) {
                acc[fr][fc] = __builtin_amdgcn_mfma_f32_16x16x32_f16(Ah[fr], Bh[fc], acc[fr][fc], 0, 0, 0);
                acc[fr][fc] = __builtin_amdgcn_mfma_f32_16x16x32_f16(Ah[fr], Bl[fc], acc[fr][fc], 0, 0, 0);
                acc[fr][fc] = __builtin_amdgcn_mfma_f32_16x16x32_f16(Al[fr], Bh[fc], acc[fr][fc], 0, 0, 0);
            }

        __syncthreads();
    }

    // ---- norms ----
    s_part[tid] = ps;
    __syncthreads();
    if (tid < 128) {
        const int sl = tid >> 6, r = tid & 63;
        const int src = (sl && !diag) ? 128 + 2 * r : 2 * r;
        float ssum = s_part[src] + s_part[src + 1];
        s_inv[sl][r] = 1.0 / (sqrt((double)ssum) + 1e-5);
    }
    __syncthreads();

    float* Gb = G + (size_t)batch * TRI;
    #pragma unroll
    for (int fr = 0; fr < 2; ++fr)
        #pragma unroll
        for (int fc = 0; fc < 2; ++fc)
            #pragma unroll
            for (int reg = 0; reg < 4; ++reg) {
                const int il = 32 * wr + 16 * fr + 4 * g + reg;   // D row (m89)
                const int jl = 32 * wc + 16 * fc + c16;           // D col (m89)
                const int i = i0 + il, j = j0 + jl;
                if (i <= j && j < NN)
                    Gb[tri_base(i) + (j - i)] =
                        (float)(fabs((double)acc[fr][fc][reg]) * s_inv[0][il] * s_inv[1][jl]);
            }

    if (DOSEL) {
        // ---- completion counter: last of the 15 blocks runs selection ----
        __threadfence();                     // release my G stores (device scope)
        __syncthreads();                     // all threads' stores + fences done
        if (tid == 0)
            s_flag = (atomicAdd(&cnt[batch], 1) == NTILES - 1);
        __syncthreads();
        if (s_flag) {
            __threadfence();                 // acquire: observe peers' G stores
            if (tid < 64)
                select_wave_tri(Gb, tid, s_sorted);
            __syncthreads();
            if (tid < KK)
                idx[batch * KK + tid] = s_sorted[tid];
        }
    }
}

// ---------------- 2. gather-only, 4 blocks per batch ----------------
__global__ __launch_bounds__(256) void kgath(const int* __restrict__ idx,
                                             const float* __restrict__ video,
                                             const float* __restrict__ audio,
                                             float* __restrict__ out_v,
                                             float* __restrict__ out_a) {
    const int b = blockIdx.x >> 2, quar = blockIdx.x & 3, tid = threadIdx.x;
    __shared__ int s_idx[KK];
    if (tid < KK) s_idx[tid] = idx[b * KK + tid];
    __syncthreads();

    const float4* vb4 = (const float4*)(video + (size_t)b * NN * DV);
    float4* ov4 = (float4*)(out_v + (size_t)b * KK * DV);
    const int vbeg = quar * 4096, vend = vbeg + 4096;      // KK*DV/4 = 16384
    #pragma unroll 4
    for (int t = vbeg + tid; t < vend; t += 256) {
        int k = t >> 8, c = t & 255;                       // 256 f4 per row
        ov4[t] = vb4[s_idx[k] * (DV / 4) + c];
    }
    const float4* ab4 = (const float4*)(audio + (size_t)b * NN * DA);
    float4* oa4 = (float4*)(out_a + (size_t)b * KK * DA);
    const int abeg = quar * 512, aend = abeg + 512;        // KK*DA/4 = 2048
    for (int t = abeg + tid; t < aend; t += 256) {
        int k = t >> 5, c = t & 31;                        // 32 f4 per row
        oa4[t] = ab4[s_idx[k] * (DA / 4) + c];
    }
}

// ---------------- fallback split path (G in out_v region) ----------------
__global__ __launch_bounds__(64) void kselect(const float* __restrict__ G,
                                              float* __restrict__ out_a) {
    __shared__ int s_sorted[KK];
    select_wave_tri(G + (size_t)blockIdx.x * TRI, threadIdx.x, s_sorted);
    __syncthreads();
    ((int*)(out_a + (size_t)blockIdx.x * KK * DA))[threadIdx.x] = s_sorted[threadIdx.x];
}

__global__ __launch_bounds__(256) void kgather(const float* __restrict__ video,
                                               const float* __restrict__ audio,
                                               float* __restrict__ out_v,
                                               float* __restrict__ out_a) {
    int b = blockIdx.x, tid = threadIdx.x;
    __shared__ int s_idx[KK];
    const int* idxp = (const int*)(out_a + (size_t)b * KK * DA);
    if (tid < KK) s_idx[tid] = idxp[tid];
    __syncthreads();

    const float4* vb4 = (const float4*)(video + (size_t)b * NN * DV);
    float4* ov4 = (float4*)(out_v + (size_t)b * KK * DV);
    #pragma unroll 4
    for (int t = tid; t < KK * DV / 4; t += 256) {
        int k = t >> 8, c = t & 255;
        ov4[t] = vb4[s_idx[k] * (DV / 4) + c];
    }
    const float4* ab4 = (const float4*)(audio + (size_t)b * NN * DA);
    float4* oa4 = (float4*)(out_a + (size_t)b * KK * DA);
    for (int t = tid; t < KK * DA / 4; t += 256) {
        int k = t >> 5, c = t & 31;
        oa4[t] = ab4[s_idx[k] * (DA / 4) + c];
    }
}

extern "C" void kernel_launch(void* const* d_in, const int* in_sizes, int n_in,
                              void* d_out, int out_size, void* d_ws, size_t ws_size,
                              hipStream_t stream) {
    const float* video = (const float*)d_in[0];
    const float* audio = (const float*)d_in[1];
    float* out   = (float*)d_out;
    float* out_v = out;
    float* out_a = out + (size_t)BB * KK * DV;

    if (ws_size >= WS_NEED) {
        float* G = (float*)d_ws;
        int* cnt = (int*)((char*)d_ws + CNT_OFF);
        int* idx = (int*)((char*)d_ws + IDX_OFF);
        hipMemsetAsync(cnt, 0, 512, stream);               // per-launch counters
        kgram<true><<<NTILES * BB, 256, 0, stream>>>(video, G, cnt, idx);
        kgath<<<4 * BB, 256, 0, stream>>>(idx, video, audio, out_v, out_a);
    } else {
        float* G = out;
        kgram<false><<<NTILES * BB, 256, 0, stream>>>(video, G, nullptr, nullptr);
        kselect<<<BB, 64, 0, stream>>>(G, out_a);
        kgather<<<BB, 256, 0, stream>>>(video, audio, out_v, out_a);
    }
}

// Round 17
// 279.932 us; speedup vs baseline: 1.7563x; 1.7563x over previous
//
#include <hip/hip_runtime.h>
#include <math.h>

// Greedy farthest-point selection via precomputed Gram triangle.
// kgram : R9's proven engine (64x64-tile MFMA f16 2-way split, dbuf LDS, one
//         barrier/chunk, reg prefetch 2 ahead) + T2 XOR slot-swizzle on the
//         staging layout: phys_slot = logical_slot ^ (row&7), applied on the
//         write AND both b64 fragment reads -> breaks the systematic 4-way
//         write bank collision (R9: 6.55M conflict-cycles ~ 25% of chunk
//         time). MFMA inputs bit-identical (storage permutation only).
// kfused: R9's proven selection (wave 0) + gather (all waves), one block/batch.
// Fallback (tiny ws): split path, G in out_v region (kernels serialize).

constexpr int BB = 128, NN = 300, DV = 1024, DA = 128, KK = 64;
constexpr int TRI = NN * (NN + 1) / 2;        // 45150
constexpr int TB = 64;
constexpr int NTILES = 15;
constexpr int KC = 32;
constexpr int NCH = DV / KC;                  // 32 chunks
constexpr int LDH = 36;                       // f16 row stride: 72 B

__device__ __constant__ int c_ib[NTILES] = {0,0,0,0,0, 1,1,1,1, 2,2,2, 3,3, 4};
__device__ __constant__ int c_jb[NTILES] = {0,1,2,3,4, 1,2,3,4, 2,3,4, 3,4, 4};

typedef _Float16 f16x8 __attribute__((ext_vector_type(8)));
typedef float    f32x4 __attribute__((ext_vector_type(4)));

union H4 { _Float16 h[4]; uint2 u; };
union F8 { uint2 u2[2]; f16x8 v; };

__device__ __forceinline__ int tri_base(int i) { return i * NN - (i * (i - 1)) / 2; }

// ---------------- 1. kgram: 64-tile, dbuf, 4 waves, slot-swizzled ----------
__global__ __launch_bounds__(256) void kgram(const float* __restrict__ video,
                                             float* __restrict__ G) {
    const int bid  = blockIdx.x;
    const int swz  = (bid & 7) * 240 + (bid >> 3);      // bijective: 1920=8*240
    const int batch = swz / 15;
    const int tile  = swz - batch * 15;
    const int i0 = c_ib[tile] * TB, j0 = c_jb[tile] * TB;
    const bool diag = (i0 == j0);
    const int tid = threadIdx.x;

    __shared__ _Float16 sH[2][4][TB][LDH];   // [buf][A-hi,A-lo,B-hi,B-lo] 36.9 KB
    __shared__ float    s_part[256];
    __shared__ double   s_inv[2][TB];

    const float* vb = video + (size_t)batch * NN * DV;

    // staging role: thread -> (slab, row, k-half); 16 floats per chunk
    const int slab  = tid >> 7;           // 0=A(i-rows), 1=B(j-rows)
    const int lrow  = (tid >> 1) & 63;
    const int khalf = tid & 1;
    const int grow  = (slab ? j0 : i0) + lrow;
    const bool rok  = grow < NN;
    const bool stage_on = !(diag && slab == 1);   // diag: B slab = A slab
    const float4* srcb4 = (const float4*)(vb + (size_t)(rok ? grow : 0) * DV);
    const int qbase = khalf * 4;          // float4 index within chunk
    const int wm = lrow & 7;              // write-side swizzle mask

    // compute role
    const int lane = tid & 63, w = tid >> 6;
    const int wr = w >> 1, wc = w & 1;
    const int g = lane >> 4, c16 = lane & 15;
    const int bplane = diag ? 0 : 2;

    f32x4 acc[2][2];
    #pragma unroll
    for (int fr = 0; fr < 2; ++fr)
        #pragma unroll
        for (int fc = 0; fc < 2; ++fc) acc[fr][fc] = (f32x4){0.f, 0.f, 0.f, 0.f};

    float ps = 0.f;
    float4 ld[4];
    const float4 z4 = make_float4(0.f, 0.f, 0.f, 0.f);

    // stage from ld regs into buffer bf; slot-swizzled: phys = ls ^ (row&7)
    auto stage_write = [&](int bf) {
        #pragma unroll
        for (int q = 0; q < 4; ++q) {
            float4 v = ld[q];
            ps = fmaf(v.x, v.x, fmaf(v.y, v.y, fmaf(v.z, v.z, fmaf(v.w, v.w, ps))));
            H4 hi, lo;
            _Float16 h0 = (_Float16)v.x, h1 = (_Float16)v.y,
                     h2 = (_Float16)v.z, h3 = (_Float16)v.w;
            hi.h[0] = h0; hi.h[1] = h1; hi.h[2] = h2; hi.h[3] = h3;
            lo.h[0] = (_Float16)(v.x - (float)h0);
            lo.h[1] = (_Float16)(v.y - (float)h1);
            lo.h[2] = (_Float16)(v.z - (float)h2);
            lo.h[3] = (_Float16)(v.w - (float)h3);
            const int p = ((khalf * 4 + q) ^ wm) * 4;    // swizzled 8B slot
            *(uint2*)&sH[bf][slab * 2 + 0][lrow][p] = hi.u;
            *(uint2*)&sH[bf][slab * 2 + 1][lrow][p] = lo.u;
        }
    };

    // prologue: chunk 0 staged into buf 0; chunk 1 in regs
    if (stage_on) {
        #pragma unroll
        for (int q = 0; q < 4; ++q) ld[q] = rok ? srcb4[qbase + q] : z4;
        stage_write(0);
        #pragma unroll
        for (int q = 0; q < 4; ++q) ld[q] = rok ? srcb4[8 + qbase + q] : z4;
    }
    __syncthreads();

    for (int kc = 0; kc < NCH; ++kc) {
        const int cur = kc & 1, nxt = cur ^ 1;

        if (stage_on && kc < NCH - 1) stage_write(nxt);
        if (stage_on && kc < NCH - 2) {
            #pragma unroll
            for (int q = 0; q < 4; ++q)
                ld[q] = rok ? srcb4[(kc + 2) * 8 + qbase + q] : z4;
        }

        // fragment reads: logical slots g and 4+g through the same XOR
        f16x8 Ah[2], Al[2], Bh[2], Bl[2];
        #pragma unroll
        for (int fr = 0; fr < 2; ++fr) {
            const int row = 32 * wr + 16 * fr + c16;
            const int m = row & 7;
            const int p1 = (g ^ m) * 4, p2 = ((4 + g) ^ m) * 4;
            F8 t;
            t.u2[0] = *(const uint2*)&sH[cur][0][row][p1];
            t.u2[1] = *(const uint2*)&sH[cur][0][row][p2];
            Ah[fr] = t.v;
            t.u2[0] = *(const uint2*)&sH[cur][1][row][p1];
            t.u2[1] = *(const uint2*)&sH[cur][1][row][p2];
            Al[fr] = t.v;
        }
        #pragma unroll
        for (int fc = 0; fc < 2; ++fc) {
            const int row = 32 * wc + 16 * fc + c16;
            const int m = row & 7;
            const int p1 = (g ^ m) * 4, p2 = ((4 + g) ^ m) * 4;
            F8 t;
            t.u2[0] = *(const uint2*)&sH[cur][bplane + 0][row][p1];
            t.u2[1] = *(const uint2*)&sH[cur][bplane + 0][row][p2];
            Bh[fc] = t.v;
            t.u2[0] = *(const uint2*)&sH[cur][bplane + 1][row][p1];
            t.u2[1] = *(const uint2*)&sH[cur][bplane + 1][row][p2];
            Bl[fc] = t.v;
        }
        #pragma unroll
        for (int fr = 0; fr < 2; ++fr)
            #pragma unroll
            for (int fc = 0; fc < 2; ++fc) {
                acc[fr][fc] = __builtin_amdgcn_mfma_f32_16x16x32_f16(Ah[fr], Bh[fc], acc[fr][fc], 0, 0, 0);
                acc[fr][fc] = __builtin_amdgcn_mfma_f32_16x16x32_f16(Ah[fr], Bl[fc], acc[fr][fc], 0, 0, 0);
                acc[fr][fc] = __builtin_amdgcn_mfma_f32_16x16x32_f16(Al[fr], Bh[fc], acc[fr][fc], 0, 0, 0);
            }

        __syncthreads();   // one barrier per chunk: nxt fully staged, cur consumed
    }

    // ---- norms ----
    s_part[tid] = ps;
    __syncthreads();
    if (tid < 128) {
        const int sl = tid >> 6, r = tid & 63;
        const int src = (sl && !diag) ? 128 + 2 * r : 2 * r;   // diag: reuse A
        float ssum = s_part[src] + s_part[src + 1];
        s_inv[sl][r] = 1.0 / (sqrt((double)ssum) + 1e-5);
    }
    __syncthreads();

    float* Gb = G + (size_t)batch * TRI;
    #pragma unroll
    for (int fr = 0; fr < 2; ++fr)
        #pragma unroll
        for (int fc = 0; fc < 2; ++fc)
            #pragma unroll
            for (int reg = 0; reg < 4; ++reg) {
                const int il = 32 * wr + 16 * fr + 4 * g + reg;   // D row (m89)
                const int jl = 32 * wc + 16 * fc + c16;           // D col (m89)
                const int i = i0 + il, j = j0 + jl;
                if (i <= j && j < NN)
                    Gb[tri_base(i) + (j - i)] =
                        (float)(fabs((double)acc[fr][fc][reg]) * s_inv[0][il] * s_inv[1][jl]);
            }
}

// ---- device helper: greedy selection for one batch, one wave ----
__device__ __forceinline__ void select_wave_tri(const float* __restrict__ Gb,
                                                int lane, int* s_sorted) {
    float best[5];
    int myidx = 0;

    #pragma unroll
    for (int q = 0; q < 5; ++q) {
        int r = lane + 64 * q;
        best[q] = (r < NN) ? Gb[r] : 3.4e38f;
    }

    int last;
    {
        float v = INFINITY; int ri = 1 << 30;
        #pragma unroll
        for (int q = 0; q < 5; ++q)
            if (best[q] < v) { v = best[q]; ri = lane + 64 * q; }
        #pragma unroll
        for (int off = 32; off >= 1; off >>= 1) {
            float ov = __shfl_xor(v, off, 64); int oi = __shfl_xor(ri, off, 64);
            if (ov < v || (ov == v && oi < ri)) { v = ov; ri = oi; }
        }
        last = ri;
    }
    if (lane == 1) myidx = last;

    for (int t = 2; t < KK; ++t) {
        #pragma unroll
        for (int q = 0; q < 5; ++q) {
            int r = lane + 64 * q;
            if (r < NN) {
                int i = min(last, r), j = max(last, r);
                best[q] = fmaxf(best[q], Gb[tri_base(i) + (j - i)]);
            }
        }
        float v = INFINITY; int ri = 1 << 30;
        #pragma unroll
        for (int q = 0; q < 5; ++q)
            if (best[q] < v) { v = best[q]; ri = lane + 64 * q; }
        #pragma unroll
        for (int off = 32; off >= 1; off >>= 1) {
            float ov = __shfl_xor(v, off, 64); int oi = __shfl_xor(ri, off, 64);
            if (ov < v || (ov == v && oi < ri)) { v = ov; ri = oi; }
        }
        last = ri;
        if (lane == t) myidx = last;
    }

    int rank = 0;
    for (int j = 0; j < KK; ++j) {
        int oj = __shfl(myidx, j, 64);
        rank += (oj < myidx) || (oj == myidx && j < lane);
    }
    s_sorted[rank] = myidx;
}

// ---------------- 2. fused selection + gather ----------------
__global__ __launch_bounds__(256) void kfused(const float* __restrict__ G,
                                              const float* __restrict__ video,
                                              const float* __restrict__ audio,
                                              float* __restrict__ out_v,
                                              float* __restrict__ out_a) {
    const int b = blockIdx.x, tid = threadIdx.x;
    __shared__ int s_sorted[KK];

    if (tid < 64)
        select_wave_tri(G + (size_t)b * TRI, tid, s_sorted);
    __syncthreads();

    const float4* vb4 = (const float4*)(video + (size_t)b * NN * DV);
    float4* ov4 = (float4*)(out_v + (size_t)b * KK * DV);
    #pragma unroll 4
    for (int t = tid; t < KK * DV / 4; t += 256) {
        int k = t >> 8, c = t & 255;
        ov4[t] = vb4[s_sorted[k] * (DV / 4) + c];
    }
    const float4* ab4 = (const float4*)(audio + (size_t)b * NN * DA);
    float4* oa4 = (float4*)(out_a + (size_t)b * KK * DA);
    for (int t = tid; t < KK * DA / 4; t += 256) {
        int k = t >> 5, c = t & 31;
        oa4[t] = ab4[s_sorted[k] * (DA / 4) + c];
    }
}

// ---------------- fallback split path (G in out_v region) ----------------
__global__ __launch_bounds__(64) void kselect(const float* __restrict__ G,
                                              float* __restrict__ out_a) {
    __shared__ int s_sorted[KK];
    select_wave_tri(G + (size_t)blockIdx.x * TRI, threadIdx.x, s_sorted);
    __syncthreads();
    ((int*)(out_a + (size_t)blockIdx.x * KK * DA))[threadIdx.x] = s_sorted[threadIdx.x];
}

__global__ __launch_bounds__(256) void kgather(const float* __restrict__ video,
                                               const float* __restrict__ audio,
                                               float* __restrict__ out_v,
                                               float* __restrict__ out_a) {
    int b = blockIdx.x, tid = threadIdx.x;
    __shared__ int s_idx[KK];
    const int* idxp = (const int*)(out_a + (size_t)b * KK * DA);
    if (tid < KK) s_idx[tid] = idxp[tid];
    __syncthreads();

    const float4* vb4 = (const float4*)(video + (size_t)b * NN * DV);
    float4* ov4 = (float4*)(out_v + (size_t)b * KK * DV);
    #pragma unroll 4
    for (int t = tid; t < KK * DV / 4; t += 256) {
        int k = t >> 8, c = t & 255;
        ov4[t] = vb4[s_idx[k] * (DV / 4) + c];
    }
    const float4* ab4 = (const float4*)(audio + (size_t)b * NN * DA);
    float4* oa4 = (float4*)(out_a + (size_t)b * KK * DA);
    for (int t = tid; t < KK * DA / 4; t += 256) {
        int k = t >> 5, c = t & 31;
        oa4[t] = ab4[s_idx[k] * (DA / 4) + c];
    }
}

extern "C" void kernel_launch(void* const* d_in, const int* in_sizes, int n_in,
                              void* d_out, int out_size, void* d_ws, size_t ws_size,
                              hipStream_t stream) {
    const float* video = (const float*)d_in[0];
    const float* audio = (const float*)d_in[1];
    float* out   = (float*)d_out;
    float* out_v = out;
    float* out_a = out + (size_t)BB * KK * DV;

    const size_t g_bytes = (size_t)BB * TRI * sizeof(float);   // 23.1 MB

    if (ws_size >= g_bytes) {
        float* G = (float*)d_ws;
        kgram <<<NTILES * BB, 256, 0, stream>>>(video, G);
        kfused<<<BB, 256, 0, stream>>>(G, video, audio, out_v, out_a);
    } else {
        float* G = out;
        kgram  <<<NTILES * BB, 256, 0, stream>>>(video, G);
        kselect<<<BB, 64, 0, stream>>>(G, out_a);
        kgather<<<BB, 256, 0, stream>>>(video, audio, out_v, out_a);
    }
}